// Round 23
// baseline (762.176 us; speedup 1.0000x reference)
//
#include <hip/hip_runtime.h>

// RuleGraphNet: 2x TripleConv(+mlp), N=50000 nodes, E=800000 edges.
// Pipeline: BOTH convs' edge mid-GEMMs in one dispatch (mt_both: 2x128-row
// tiles per block with BOTH tiles' A fragments gathered up-front so tile B's
// HBM latency hides under tile A's compute; eatt rows gathered once via eord,
// converted bf16, reused for conv1 AND conv2; W fragments double-buffered
// across the nt loop; wave-private LDS C-staging + copy-out, no barriers);
// MT1/MT2 CSR-ordered -> sequential aggregation reads; NT bf16; aggregation
// wave owns 1 dst node, lane owns a column pair, register accumulation over
// both phases, self fused. All dense GEMMs use pre-transposed bf16 weight
// tables, single-tile blocks (RT=1); K%4!=0 staging path vectorized.

#define NN 50000
#define NE 800000
#define EHALF 400000
#define NN2 100000
#define GB 8            // edges batched per gather group

typedef __attribute__((ext_vector_type(4))) float  f32x4;
typedef __attribute__((ext_vector_type(8))) __bf16 bf16x8;
typedef __attribute__((ext_vector_type(4))) __bf16 bf16x4;

__device__ __forceinline__ float bf16lo(unsigned u) {
    union { unsigned u; float f; } c; c.u = u << 16; return c.f;
}
__device__ __forceinline__ float bf16hi(unsigned u) {
    union { unsigned u; float f; } c; c.u = u & 0xffff0000u; return c.f;
}

// ------- generic bf16 MFMA GEMM, W from pre-transposed bf16 table ---------
template<int K, bool OBF16>
__global__ __launch_bounds__(256)
void mm_bf16t(const float* __restrict__ A, const __bf16* __restrict__ Wtt,
              const float* __restrict__ bias, void* __restrict__ Outp,
              int M, int N, int ldo, int RT, int relu)
{
    __shared__ __align__(16) __bf16 et[128 * 128];
    const int t = threadIdx.x;
    const int lane = t & 63, w = t >> 6;
    const int mh = w & 1, nh = w >> 1;
    const int l15 = lane & 15, l4 = lane >> 4;
    const int cb = blockIdx.y * 64;

    bf16x8 wf[2][4];
    const int colbase = cb + nh * 32 + l15;
    #pragma unroll
    for (int nt = 0; nt < 2; ++nt)
        #pragma unroll
        for (int ks = 0; ks < 4; ++ks)
            wf[nt][ks] = *(const bf16x8*)(Wtt + (colbase + nt * 16) * 128 +
                                          ks * 32 + l4 * 8);
    float bv[2] = {0.f, 0.f};
    if (bias) {
        #pragma unroll
        for (int nt = 0; nt < 2; ++nt) {
            int col = colbase + nt * 16;
            if (col < N) bv[nt] = bias[col];
        }
    }

    for (int it = 0; it < RT; ++it) {
        const int row0 = (blockIdx.x * RT + it) * 128;
        if (row0 >= M) break;
        __syncthreads();
        if constexpr (K % 4 == 0) {
            constexpr int QK = K / 4;
            for (int i = t; i < 128 * QK; i += 256) {
                int row = i / QK, q = i - row * QK;
                int gr = row0 + row;
                float4 v = {0.f, 0.f, 0.f, 0.f};
                if (gr < M) v = *(const float4*)(A + (size_t)gr * K + q * 4);
                bf16x4 b;
                b[0] = (__bf16)v.x; b[1] = (__bf16)v.y;
                b[2] = (__bf16)v.z; b[3] = (__bf16)v.w;
                *(bf16x4*)(et + row * 128 + ((q * 4) ^ ((row & 7) << 3))) = b;
            }
            constexpr int QP = (128 - K) / 4;
            if constexpr (QP > 0) {
                for (int i = t; i < 128 * QP; i += 256) {
                    int row = i / QP, q = QK + (i - (i / QP) * QP);
                    bf16x4 z;
                    z[0] = (__bf16)0.f; z[1] = (__bf16)0.f;
                    z[2] = (__bf16)0.f; z[3] = (__bf16)0.f;
                    *(bf16x4*)(et + row * 128 + ((q * 4) ^ ((row & 7) << 3))) = z;
                }
            }
        } else {
            // vectorized-chunk staging for K % 4 != 0 (rows only 4B-aligned)
            for (int i = t; i < 128 * 32; i += 256) {
                int row = i >> 5, q = i & 31;
                int gr = row0 + row;
                int k0 = q * 4;
                float4 v = {0.f, 0.f, 0.f, 0.f};
                if (gr < M && k0 < K) {
                    const float* ap = A + (size_t)gr * K + k0;
                    if (k0 + 4 <= K) {
                        v.x = ap[0]; v.y = ap[1]; v.z = ap[2]; v.w = ap[3];
                    } else {
                        v.x = ap[0];
                        if (k0 + 1 < K) v.y = ap[1];
                        if (k0 + 2 < K) v.z = ap[2];
                    }
                }
                bf16x4 b;
                b[0] = (__bf16)v.x; b[1] = (__bf16)v.y;
                b[2] = (__bf16)v.z; b[3] = (__bf16)v.w;
                *(bf16x4*)(et + row * 128 + ((q * 4) ^ ((row & 7) << 3))) = b;
            }
        }
        __syncthreads();

        f32x4 c[4][2] = {};
        #pragma unroll
        for (int ks = 0; ks < 4; ++ks) {
            #pragma unroll
            for (int mt = 0; mt < 4; ++mt) {
                int arow = mh * 64 + mt * 16 + l15;
                bf16x8 a = *(const bf16x8*)(et + arow * 128 +
                                            ((ks * 32 + l4 * 8) ^ ((l15 & 7) << 3)));
                c[mt][0] = __builtin_amdgcn_mfma_f32_16x16x32_bf16(a, wf[0][ks], c[mt][0], 0, 0, 0);
                c[mt][1] = __builtin_amdgcn_mfma_f32_16x16x32_bf16(a, wf[1][ks], c[mt][1], 0, 0, 0);
            }
        }

        #pragma unroll
        for (int mt = 0; mt < 4; ++mt) {
            #pragma unroll
            for (int nt = 0; nt < 2; ++nt) {
                int col = colbase + nt * 16;
                #pragma unroll
                for (int r = 0; r < 4; ++r) {
                    int row = row0 + mh * 64 + mt * 16 + l4 * 4 + r;
                    if constexpr (OBF16) {
                        if (row < M && col < ldo)
                            ((__bf16*)Outp)[(size_t)row * ldo + col] =
                                (__bf16)(c[mt][nt][r] + bv[nt]);
                    } else {
                        if (row < M && col < N) {
                            float v = c[mt][nt][r] + bv[nt];
                            if (relu) v = fmaxf(v, 0.f);
                            ((float*)Outp)[(size_t)row * ldo + col] = v;
                        }
                    }
                }
            }
        }
    }
}

// ---------------- CSR build (edges sorted by dst, per half) ----------------
__global__ void zero_ints(int* __restrict__ p, int n)
{
    int i = blockIdx.x * 256 + threadIdx.x;
    if (i < n) p[i] = 0;
}

__global__ void count_edges(const int* __restrict__ dst, int* __restrict__ cnt)
{
    int e = blockIdx.x * 256 + threadIdx.x;
    if (e < NE) atomicAdd(&cnt[dst[e] + (e >= EHALF ? NN : 0)], 1);
}

__global__ void scan_blocks(const int* __restrict__ cnt, int* __restrict__ off,
                            int* __restrict__ bsum, int n)
{
    __shared__ int s[256];
    int t = threadIdx.x, g = blockIdx.x * 256 + t;
    int v = (g < n) ? cnt[g] : 0;
    s[t] = v; __syncthreads();
    for (int d = 1; d < 256; d <<= 1) {
        int add = (t >= d) ? s[t - d] : 0;
        __syncthreads();
        s[t] += add;
        __syncthreads();
    }
    if (g < n) off[g] = s[t] - v;
    if (t == 255) bsum[blockIdx.x] = s[255];
}

__global__ void scan_bsum(int* __restrict__ bsum, int nb)
{
    __shared__ int s[512];
    int t = threadIdx.x;
    int v = (t < nb) ? bsum[t] : 0;
    s[t] = v; __syncthreads();
    for (int d = 1; d < 512; d <<= 1) {
        int add = (t >= d) ? s[t - d] : 0;
        __syncthreads();
        s[t] += add;
        __syncthreads();
    }
    if (t < nb) bsum[t] = s[t] - v;
}

__global__ void scan_add(int* __restrict__ off, const int* __restrict__ bsum,
                         int* __restrict__ cur, int n)
{
    int g = blockIdx.x * 256 + threadIdx.x;
    if (g < n) { int o = off[g] + bsum[blockIdx.x]; off[g] = o; cur[g] = o; }
}

__global__ void scatter_edges(const int* __restrict__ eidx, int* __restrict__ cur,
                              int* __restrict__ srcp, int* __restrict__ eord)
{
    int e = blockIdx.x * 256 + threadIdx.x;
    if (e < NE) {
        int s = eidx[e], d = eidx[NE + e];
        int pos = atomicAdd(&cur[d + (e >= EHALF ? NN : 0)], 1);
        srcp[pos] = s;
        eord[pos] = e;
    }
}

// ----- mt_both: 2 row-tiles per block, A for BOTH tiles gathered upfront --
// grid 3125: block owns 256 CSR rows (two 128-row tiles; per-tile half since
// 128 | EHALF). Wave w owns rows [w*32,+32) of each tile. Both tiles' eatt
// rows gathered via eord at block start (tile B's latency hides under tile
// A's compute); converted bf16 once, reused for conv1 and conv2. W fragments
// double-buffered across the 7-iter nt loop. C staged in LDS (stride 116);
// wave-private copy-out, no barriers.
__global__ __launch_bounds__(256, 3)
void mt_both(const float* __restrict__ eatt,   // [NE][100] original order
             const int* __restrict__ eord,     // [NE] CSR pos -> edge id
             const __bf16* __restrict__ Wt,    // [4][128][128]
             __bf16* __restrict__ MT1,         // [NE][112] CSR order
             __bf16* __restrict__ MT2)         // [NE][112] CSR order
{
    __shared__ __align__(16) __bf16 ct[128 * 116];   // 29.7 KB
    const int t = threadIdx.x;
    const int lane = t & 63, w = t >> 6;
    const int l15 = lane & 15, l4 = lane >> 4;
    const int rbase = w * 32;
    const int wko = l4 * 8;
    const size_t base = (size_t)blockIdx.x * 256;

    // gather + convert A fragments for BOTH tiles upfront
    bf16x8 afA[2][4], afB[2][4];
    {
        const float* epA[2]; const float* epB[2];
        #pragma unroll
        for (int mt = 0; mt < 2; ++mt) {
            epA[mt] = eatt + (size_t)eord[base + rbase + mt * 16 + l15] * 100;
            epB[mt] = eatt + (size_t)eord[base + 128 + rbase + mt * 16 + l15] * 100;
        }
        #pragma unroll
        for (int ks = 0; ks < 4; ++ks) {
            const int bk = ks * 32 + wko;
            #pragma unroll
            for (int mt = 0; mt < 2; ++mt) {
                float4 a0 = {0.f,0.f,0.f,0.f}, a1 = {0.f,0.f,0.f,0.f};
                float4 b0 = {0.f,0.f,0.f,0.f}, b1 = {0.f,0.f,0.f,0.f};
                if (bk < 100) {
                    a0 = *(const float4*)(epA[mt] + bk);
                    b0 = *(const float4*)(epB[mt] + bk);
                }
                if (bk + 4 < 100) {
                    a1 = *(const float4*)(epA[mt] + bk + 4);
                    b1 = *(const float4*)(epB[mt] + bk + 4);
                }
                bf16x8 fa, fb;
                fa[0] = (__bf16)a0.x; fa[1] = (__bf16)a0.y;
                fa[2] = (__bf16)a0.z; fa[3] = (__bf16)a0.w;
                fa[4] = (__bf16)a1.x; fa[5] = (__bf16)a1.y;
                fa[6] = (__bf16)a1.z; fa[7] = (__bf16)a1.w;
                fb[0] = (__bf16)b0.x; fb[1] = (__bf16)b0.y;
                fb[2] = (__bf16)b0.z; fb[3] = (__bf16)b0.w;
                fb[4] = (__bf16)b1.x; fb[5] = (__bf16)b1.y;
                fb[6] = (__bf16)b1.z; fb[7] = (__bf16)b1.w;
                afA[mt][ks] = fa;
                afB[mt][ks] = fb;
            }
        }
    }

    auto tile = [&](const bf16x8 (&af)[2][4], size_t row0) {
        const int half = (row0 >= EHALF) ? 1 : 0;
        const __bf16* Wq0 = Wt + (size_t)half * 16384;
        const __bf16* Wq1 = Wt + (size_t)(2 + half) * 16384;

        // prime W pipeline: conv0, nt=0
        bf16x8 wfp[4];
        #pragma unroll
        for (int ks = 0; ks < 4; ++ks)
            wfp[ks] = *(const bf16x8*)(Wq0 + l15 * 128 + ks * 32 + wko);

        #pragma unroll 1
        for (int conv = 0; conv < 2; ++conv) {
            const __bf16* Wq = conv ? Wq1 : Wq0;
            __bf16* MT = conv ? MT2 : MT1;

            #pragma unroll 1
            for (int nt = 0; nt < 7; ++nt) {
                const int col = nt * 16 + l15;
                bf16x8 wfn[4];
                #pragma unroll
                for (int ks = 0; ks < 4; ++ks) wfn[ks] = wfp[ks];
                const __bf16* pf = (nt < 6) ? (Wq + (col + 16) * 128)
                                 : (conv == 0 ? (Wq1 + l15 * 128) : nullptr);
                if (pf) {
                    #pragma unroll
                    for (int ks = 0; ks < 4; ++ks)
                        wfp[ks] = *(const bf16x8*)(pf + ks * 32 + wko);
                }
                f32x4 c4[2] = {};
                #pragma unroll
                for (int ks = 0; ks < 4; ++ks) {
                    c4[0] = __builtin_amdgcn_mfma_f32_16x16x32_bf16(
                        af[0][ks], wfn[ks], c4[0], 0, 0, 0);
                    c4[1] = __builtin_amdgcn_mfma_f32_16x16x32_bf16(
                        af[1][ks], wfn[ks], c4[1], 0, 0, 0);
                }
                #pragma unroll
                for (int mt = 0; mt < 2; ++mt)
                    #pragma unroll
                    for (int r = 0; r < 4; ++r)
                        ct[(rbase + mt * 16 + l4 * 4 + r) * 116 + col] =
                            (__bf16)c4[mt][r];
            }

            // wave-private copy-out: rows [rbase,+32) x cols 0..111
            __bf16* gout = MT + (row0 + rbase) * 112;
            #pragma unroll
            for (int k = 0; k < 14; ++k) {
                int i = lane + 64 * k;
                int row = i / 28, ch = i - row * 28;
                *(uint2*)(gout + row * 112 + ch * 4) =
                    *(const uint2*)(ct + (rbase + row) * 116 + ch * 4);
            }
        }
    };

    tile(afA, base);
    tile(afB, base + 128);
}

// ---------------- edge_aggr3: both phases, register accumulation ----------
// MT is CSR-ordered: row index == CSR position (sequential reads). Wave owns
// ONE dst node; lane owns column pair. NT[dst] once per phase; self fused.
template<int ND, int NTS>
__global__ __launch_bounds__(256)
void edge_aggr3(const __bf16* __restrict__ MT,    // [NE][112] CSR order
                const int* __restrict__ srcp,     // [NE] src per CSR position
                const int* __restrict__ off,      // [NN2]
                const __bf16* __restrict__ NT,    // [NN][NTS] bf16
                const float* __restrict__ self,   // [NN][ND] fp32
                float* __restrict__ aggr,         // [NN][112]
                int blkd0, int blks0, int blkd1, int blks1)
{
    const int t = threadIdx.x;
    const int lane = t & 63, wv = t >> 6;
    const int c0 = lane * 2;
    const bool a0 = c0 < ND, a1 = c0 + 1 < ND;
    const int n = blockIdx.x * 4 + wv;     // one node per wave

    float acc0 = 0.f, acc1 = 0.f;

    #pragma unroll
    for (int phase = 0; phase < 2; ++phase) {
        const int blkd = phase ? blkd1 : blkd0;
        const int blks = phase ? blks1 : blks0;
        const int idx = phase * NN + n;
        const int pb = off[idx];
        const int pe = (idx + 1 == NN2) ? NE : off[idx + 1];

        float nd0 = 0.f, nd1 = 0.f;
        if (a0) {
            unsigned nd = *(const unsigned*)(NT + (size_t)n * NTS + blkd + c0);
            nd0 = bf16lo(nd); nd1 = bf16hi(nd);
        }

        for (int p = pb; p < pe; p += GB) {
            int ok[GB], ss[GB];
            #pragma unroll
            for (int i = 0; i < GB; ++i) {
                int pp = p + i;
                ok[i] = pp < pe;
                ss[i] = ok[i] ? srcp[pp] : 0;
            }
            unsigned mtw[GB], nsw[GB];
            #pragma unroll
            for (int i = 0; i < GB; ++i) {
                mtw[i] = 0u; nsw[i] = 0u;
                if (ok[i] && a0) {
                    mtw[i] = *(const unsigned*)(MT + (size_t)(p + i) * 112 + c0);
                    nsw[i] = *(const unsigned*)(NT + (size_t)ss[i] * NTS + blks + c0);
                }
            }
            #pragma unroll
            for (int i = 0; i < GB; ++i) {
                if (!ok[i]) continue;             // wave-uniform
                acc0 += fmaxf(bf16lo(mtw[i]) + nd0 + bf16lo(nsw[i]), 0.f);
                acc1 += fmaxf(bf16hi(mtw[i]) + nd1 + bf16hi(nsw[i]), 0.f);
            }
        }
    }

    if (c0 < 112) {
        const size_t g0 = (size_t)n * 112 + c0;
        aggr[g0]     = a0 ? (acc0 + self[(size_t)n * ND + c0])     : 0.f;
        aggr[g0 + 1] = a1 ? (acc1 + self[(size_t)n * ND + c0 + 1]) : 0.f;
    }
}

// ---- weight assembly: padded concat blocks + transposed mid blocks -------
__global__ void assemble(const float* __restrict__ l1a, const float* __restrict__ l1ab,
                         const float* __restrict__ l1b, const float* __restrict__ l1bb,
                         const float* __restrict__ l2a, const float* __restrict__ l2ab,
                         const float* __restrict__ l2b, const float* __restrict__ l2bb,
                         float* __restrict__ W1, float* __restrict__ b1,
                         float* __restrict__ W2, float* __restrict__ b2,
                         __bf16* __restrict__ Wt)
{
    int i = blockIdx.x * 256 + threadIdx.x;
    if (i < 107 * 432) {
        int k = i / 432, c = i % 432;
        int q = c / 108, cc = c - q * 108;
        float v = 0.f;
        if (cc < 107) {
            if (q == 0)      v = l1a[k * 107 + cc];
            else if (q == 1) v = l1a[(207 + k) * 107 + cc];
            else if (q == 2) v = l1b[k * 107 + cc];
            else             v = l1b[(207 + k) * 107 + cc];
        }
        W1[i] = v;
    }
    if (i < 432) {
        int q = i / 108, cc = i - q * 108;
        b1[i] = (cc < 107) ? (q == 0 ? l1ab[cc] : (q == 3 ? l1bb[cc] : 0.f)) : 0.f;
    }
    if (i < 100 * 416) {
        int k = i / 416, c = i % 416;
        int q = c / 104, cc = c - q * 104;
        float v = 0.f;
        if (cc < 100) {
            if (q == 0)      v = l2a[k * 100 + cc];
            else if (q == 1) v = l2a[(200 + k) * 100 + cc];
            else if (q == 2) v = l2b[k * 100 + cc];
            else             v = l2b[(200 + k) * 100 + cc];
        }
        W2[i] = v;
    }
    if (i < 416) {
        int q = i / 104, cc = i - q * 104;
        b2[i] = (cc < 100) ? (q == 0 ? l2ab[cc] : (q == 3 ? l2bb[cc] : 0.f)) : 0.f;
    }
    if (i < 4 * 128 * 128) {
        int q = i >> 14, col = (i >> 7) & 127, k = i & 127;
        const float* Wm = (q == 0) ? l1a + 107 * 107 :
                          (q == 1) ? l1b + 107 * 107 :
                          (q == 2) ? l2a + 100 * 100 : l2b + 100 * 100;
        int ND = (q < 2) ? 107 : 100;
        float v = (k < 100 && col < ND) ? Wm[k * ND + col] : 0.f;
        Wt[i] = (__bf16)v;
    }
}

// ---- xposeW: transpose all dense-GEMM weights into bf16 [1344][128] ------
__global__ __launch_bounds__(256)
void xposeW(const float* __restrict__ W1, const float* __restrict__ W2,
            const float* __restrict__ m1w1, const float* __restrict__ m1w2,
            const float* __restrict__ m2w1, const float* __restrict__ m2w2,
            __bf16* __restrict__ WT)
{
    int i = blockIdx.x * 256 + threadIdx.x;
    if (i >= 1344 * 128) return;
    int c = i >> 7, k = i & 127;
    const float* src; int lc, cr, K, st;
    if (c < 448)      { src = W1;   lc = c;        cr = 432; K = 107; st = 432; }
    else if (c < 896) { src = W2;   lc = c - 448;  cr = 416; K = 100; st = 416; }
    else if (c < 1024){ src = m1w1; lc = c - 896;  cr = 100; K = 107; st = 100; }
    else if (c < 1152){ src = m1w2; lc = c - 1024; cr = 100; K = 100; st = 100; }
    else if (c < 1216){ src = m2w1; lc = c - 1152; cr = 64;  K = 100; st = 64;  }
    else              { src = m2w2; lc = c - 1216; cr = 100; K = 64;  st = 100; }
    float v = (lc < cr && k < K) ? src[k * st + lc] : 0.f;
    WT[i] = (__bf16)v;
}

extern "C" void kernel_launch(void* const* d_in, const int* in_sizes, int n_in,
                              void* d_out, int out_size, void* d_ws, size_t ws_size,
                              hipStream_t stream)
{
    const float* x    = (const float*)d_in[0];
    const int*   eidx = (const int*)d_in[1];
    const float* eatt = (const float*)d_in[2];
    const float* l1aw = (const float*)d_in[3];
    const float* l1ab = (const float*)d_in[4];
    const float* l1bw = (const float*)d_in[5];
    const float* l1bb = (const float*)d_in[6];
    const float* m1w1 = (const float*)d_in[7];
    const float* m1b1 = (const float*)d_in[8];
    const float* m1w2 = (const float*)d_in[9];
    const float* m1b2 = (const float*)d_in[10];
    const float* l2aw = (const float*)d_in[11];
    const float* l2ab = (const float*)d_in[12];
    const float* l2bw = (const float*)d_in[13];
    const float* l2bb = (const float*)d_in[14];
    const float* m2w1 = (const float*)d_in[15];
    const float* m2b1 = (const float*)d_in[16];
    const float* m2w2 = (const float*)d_in[17];
    const float* m2b2 = (const float*)d_in[18];
    float* out = (float*)d_out;

    // workspace layout (4-byte units), ~450 MB
    float*  ws   = (float*)d_ws;
    __bf16* NTbf = (__bf16*)ws;                         // 50000*432 bf16
    float*  bufA = ws + 10800000;                       // 50000*112 fp32
    float*  bufC = bufA + 5600000;                      // 50000*100 fp32 (h)
    float*  W1   = bufC + 5000000;                      // 46,224
    float*  b1v  = W1 + 46224;                          // 432
    float*  W2   = b1v + 432;                           // 41,600
    float*  b2v  = W2 + 41600;                          // 416
    __bf16* Wt   = (__bf16*)(b2v + 416);                // 4*128*128 bf16
    __bf16* WT   = Wt + 65536;                          // 1344*128 bf16
    int*    off  = (int*)(WT + 172032);                 // 100,000
    int*    cur  = off + NN2;                           // 100,000
    int*    bsum = cur + NN2;                           // 512
    int*    srcp = bsum + 512;                          // 800,000
    int*    eord = srcp + NE;                           // 800,000
    __bf16* MT1  = (__bf16*)(eord + NE);                // NE*112 bf16
    __bf16* MT2  = MT1 + (size_t)NE * 112;              // NE*112 bf16
    float*  bufB = (float*)MT1;                         // t1/t2 alias (MT1 consumed)

    const int* dst = eidx + NE;

    assemble<<<256, 256, 0, stream>>>(l1aw, l1ab, l1bw, l1bb, l2aw, l2ab, l2bw, l2bb,
                                      W1, b1v, W2, b2v, Wt);
    xposeW<<<672, 256, 0, stream>>>(W1, W2, m1w1, m1w2, m2w1, m2w2, WT);

    // ---- CSR build (dst-sorted, per half; emits srcp/eord) ----
    zero_ints<<<(NN2 + 255) / 256, 256, 0, stream>>>(cur, NN2);
    count_edges<<<(NE + 255) / 256, 256, 0, stream>>>(dst, cur);
    scan_blocks<<<(NN2 + 255) / 256, 256, 0, stream>>>(cur, off, bsum, NN2);
    scan_bsum<<<1, 512, 0, stream>>>(bsum, (NN2 + 255) / 256);
    scan_add<<<(NN2 + 255) / 256, 256, 0, stream>>>(off, bsum, cur, NN2);
    scatter_edges<<<(NE + 255) / 256, 256, 0, stream>>>(eidx, cur, srcp, eord);

    // ---- both convs' edge mid-GEMMs (2 tiles/block, A prefetched) ----
    mt_both<<<3125, 256, 0, stream>>>(eatt, eord, Wt, MT1, MT2);

    const int AG = NN / 4;   // 12500 blocks: 4 waves x 1 node each

    // ---- conv1 ----
    mm_bf16t<107, true><<<dim3(391, 7), 256, 0, stream>>>(x, WT, b1v, NTbf,
                                                          NN, 432, 432, 1, 0);
    edge_aggr3<107, 432><<<AG, 256, 0, stream>>>(MT1, srcp, off, NTbf, x, bufA,
                                                 0, 108, 324, 216);
    mm_bf16t<112, false><<<dim3(391, 2), 256, 0, stream>>>(bufA, WT + 896 * 128,
                                                           m1b1, bufB, NN, 100, 100, 1, 1);
    mm_bf16t<100, false><<<dim3(391, 2), 256, 0, stream>>>(bufB, WT + 1024 * 128,
                                                           m1b2, bufC, NN, 100, 100, 1, 1);

    // ---- conv2 ----  (h in bufC)
    mm_bf16t<100, true><<<dim3(391, 7), 256, 0, stream>>>(bufC, WT + 448 * 128,
                                                          b2v, NTbf, NN, 416, 416, 1, 0);
    edge_aggr3<100, 416><<<AG, 256, 0, stream>>>(MT2, srcp, off, NTbf, bufC, bufA,
                                                 0, 104, 312, 208);
    mm_bf16t<112, false><<<dim3(391, 1), 256, 0, stream>>>(bufA, WT + 1152 * 128,
                                                           m2b1, bufB, NN, 64, 64, 1, 1);
    mm_bf16t<64, false><<<dim3(391, 2), 256, 0, stream>>>(bufB, WT + 1216 * 128,
                                                          m2b2, out, NN, 100, 100, 1, 0);
}

// Round 24
// 689.611 us; speedup vs baseline: 1.1052x; 1.1052x over previous
//
#include <hip/hip_runtime.h>

// RuleGraphNet: 2x TripleConv(+mlp), N=50000 nodes, E=800000 edges.
// Best-known configuration (R22): BOTH convs' edge mid-GEMMs in one dispatch
// (mt_both: 128 CSR rows/block, wave owns 32 rows x 112 cols; eatt rows
// gathered once via eord, converted bf16 into register A fragments reused for
// conv1 AND conv2; W fragments double-buffered across the nt loop; wave-
// private LDS C-staging + copy-out, no barriers); MT1/MT2 CSR-ordered ->
// sequential aggregation reads; NT bf16; aggregation wave owns 1 dst node,
// lane owns a column pair, register accumulation over both phases, self
// fused. All dense GEMMs use pre-transposed bf16 weight tables (RT=1);
// K%4!=0 staging path vectorized.

#define NN 50000
#define NE 800000
#define EHALF 400000
#define NN2 100000
#define GB 8            // edges batched per gather group

typedef __attribute__((ext_vector_type(4))) float  f32x4;
typedef __attribute__((ext_vector_type(8))) __bf16 bf16x8;
typedef __attribute__((ext_vector_type(4))) __bf16 bf16x4;

__device__ __forceinline__ float bf16lo(unsigned u) {
    union { unsigned u; float f; } c; c.u = u << 16; return c.f;
}
__device__ __forceinline__ float bf16hi(unsigned u) {
    union { unsigned u; float f; } c; c.u = u & 0xffff0000u; return c.f;
}

// ------- generic bf16 MFMA GEMM, W from pre-transposed bf16 table ---------
template<int K, bool OBF16>
__global__ __launch_bounds__(256)
void mm_bf16t(const float* __restrict__ A, const __bf16* __restrict__ Wtt,
              const float* __restrict__ bias, void* __restrict__ Outp,
              int M, int N, int ldo, int RT, int relu)
{
    __shared__ __align__(16) __bf16 et[128 * 128];
    const int t = threadIdx.x;
    const int lane = t & 63, w = t >> 6;
    const int mh = w & 1, nh = w >> 1;
    const int l15 = lane & 15, l4 = lane >> 4;
    const int cb = blockIdx.y * 64;

    bf16x8 wf[2][4];
    const int colbase = cb + nh * 32 + l15;
    #pragma unroll
    for (int nt = 0; nt < 2; ++nt)
        #pragma unroll
        for (int ks = 0; ks < 4; ++ks)
            wf[nt][ks] = *(const bf16x8*)(Wtt + (colbase + nt * 16) * 128 +
                                          ks * 32 + l4 * 8);
    float bv[2] = {0.f, 0.f};
    if (bias) {
        #pragma unroll
        for (int nt = 0; nt < 2; ++nt) {
            int col = colbase + nt * 16;
            if (col < N) bv[nt] = bias[col];
        }
    }

    for (int it = 0; it < RT; ++it) {
        const int row0 = (blockIdx.x * RT + it) * 128;
        if (row0 >= M) break;
        __syncthreads();
        if constexpr (K % 4 == 0) {
            constexpr int QK = K / 4;
            for (int i = t; i < 128 * QK; i += 256) {
                int row = i / QK, q = i - row * QK;
                int gr = row0 + row;
                float4 v = {0.f, 0.f, 0.f, 0.f};
                if (gr < M) v = *(const float4*)(A + (size_t)gr * K + q * 4);
                bf16x4 b;
                b[0] = (__bf16)v.x; b[1] = (__bf16)v.y;
                b[2] = (__bf16)v.z; b[3] = (__bf16)v.w;
                *(bf16x4*)(et + row * 128 + ((q * 4) ^ ((row & 7) << 3))) = b;
            }
            constexpr int QP = (128 - K) / 4;
            if constexpr (QP > 0) {
                for (int i = t; i < 128 * QP; i += 256) {
                    int row = i / QP, q = QK + (i - (i / QP) * QP);
                    bf16x4 z;
                    z[0] = (__bf16)0.f; z[1] = (__bf16)0.f;
                    z[2] = (__bf16)0.f; z[3] = (__bf16)0.f;
                    *(bf16x4*)(et + row * 128 + ((q * 4) ^ ((row & 7) << 3))) = z;
                }
            }
        } else {
            // vectorized-chunk staging for K % 4 != 0 (rows only 4B-aligned)
            for (int i = t; i < 128 * 32; i += 256) {
                int row = i >> 5, q = i & 31;
                int gr = row0 + row;
                int k0 = q * 4;
                float4 v = {0.f, 0.f, 0.f, 0.f};
                if (gr < M && k0 < K) {
                    const float* ap = A + (size_t)gr * K + k0;
                    if (k0 + 4 <= K) {
                        v.x = ap[0]; v.y = ap[1]; v.z = ap[2]; v.w = ap[3];
                    } else {
                        v.x = ap[0];
                        if (k0 + 1 < K) v.y = ap[1];
                        if (k0 + 2 < K) v.z = ap[2];
                    }
                }
                bf16x4 b;
                b[0] = (__bf16)v.x; b[1] = (__bf16)v.y;
                b[2] = (__bf16)v.z; b[3] = (__bf16)v.w;
                *(bf16x4*)(et + row * 128 + ((q * 4) ^ ((row & 7) << 3))) = b;
            }
        }
        __syncthreads();

        f32x4 c[4][2] = {};
        #pragma unroll
        for (int ks = 0; ks < 4; ++ks) {
            #pragma unroll
            for (int mt = 0; mt < 4; ++mt) {
                int arow = mh * 64 + mt * 16 + l15;
                bf16x8 a = *(const bf16x8*)(et + arow * 128 +
                                            ((ks * 32 + l4 * 8) ^ ((l15 & 7) << 3)));
                c[mt][0] = __builtin_amdgcn_mfma_f32_16x16x32_bf16(a, wf[0][ks], c[mt][0], 0, 0, 0);
                c[mt][1] = __builtin_amdgcn_mfma_f32_16x16x32_bf16(a, wf[1][ks], c[mt][1], 0, 0, 0);
            }
        }

        #pragma unroll
        for (int mt = 0; mt < 4; ++mt) {
            #pragma unroll
            for (int nt = 0; nt < 2; ++nt) {
                int col = colbase + nt * 16;
                #pragma unroll
                for (int r = 0; r < 4; ++r) {
                    int row = row0 + mh * 64 + mt * 16 + l4 * 4 + r;
                    if constexpr (OBF16) {
                        if (row < M && col < ldo)
                            ((__bf16*)Outp)[(size_t)row * ldo + col] =
                                (__bf16)(c[mt][nt][r] + bv[nt]);
                    } else {
                        if (row < M && col < N) {
                            float v = c[mt][nt][r] + bv[nt];
                            if (relu) v = fmaxf(v, 0.f);
                            ((float*)Outp)[(size_t)row * ldo + col] = v;
                        }
                    }
                }
            }
        }
    }
}

// ---------------- CSR build (edges sorted by dst, per half) ----------------
__global__ void zero_ints(int* __restrict__ p, int n)
{
    int i = blockIdx.x * 256 + threadIdx.x;
    if (i < n) p[i] = 0;
}

__global__ void count_edges(const int* __restrict__ dst, int* __restrict__ cnt)
{
    int e = blockIdx.x * 256 + threadIdx.x;
    if (e < NE) atomicAdd(&cnt[dst[e] + (e >= EHALF ? NN : 0)], 1);
}

__global__ void scan_blocks(const int* __restrict__ cnt, int* __restrict__ off,
                            int* __restrict__ bsum, int n)
{
    __shared__ int s[256];
    int t = threadIdx.x, g = blockIdx.x * 256 + t;
    int v = (g < n) ? cnt[g] : 0;
    s[t] = v; __syncthreads();
    for (int d = 1; d < 256; d <<= 1) {
        int add = (t >= d) ? s[t - d] : 0;
        __syncthreads();
        s[t] += add;
        __syncthreads();
    }
    if (g < n) off[g] = s[t] - v;
    if (t == 255) bsum[blockIdx.x] = s[255];
}

__global__ void scan_bsum(int* __restrict__ bsum, int nb)
{
    __shared__ int s[512];
    int t = threadIdx.x;
    int v = (t < nb) ? bsum[t] : 0;
    s[t] = v; __syncthreads();
    for (int d = 1; d < 512; d <<= 1) {
        int add = (t >= d) ? s[t - d] : 0;
        __syncthreads();
        s[t] += add;
        __syncthreads();
    }
    if (t < nb) bsum[t] = s[t] - v;
}

__global__ void scan_add(int* __restrict__ off, const int* __restrict__ bsum,
                         int* __restrict__ cur, int n)
{
    int g = blockIdx.x * 256 + threadIdx.x;
    if (g < n) { int o = off[g] + bsum[blockIdx.x]; off[g] = o; cur[g] = o; }
}

__global__ void scatter_edges(const int* __restrict__ eidx, int* __restrict__ cur,
                              int* __restrict__ srcp, int* __restrict__ eord)
{
    int e = blockIdx.x * 256 + threadIdx.x;
    if (e < NE) {
        int s = eidx[e], d = eidx[NE + e];
        int pos = atomicAdd(&cur[d + (e >= EHALF ? NN : 0)], 1);
        srcp[pos] = s;
        eord[pos] = e;
    }
}

// ----- mt_both: both convs' edge mid-GEMMs; wave owns 32 rows x 112 cols --
// grid 6250: block owns 128 CSR rows; half = rows<EHALF ? a : b. Each eatt
// row gathered once via eord (4 lanes, disjoint 32B k-segments), converted
// bf16 into af[2][4], reused for conv1 and conv2. W fragments DOUBLE-BUFFERED
// across the 7-iter nt loop (prefetch nt+1 / next conv's nt=0 before MFMAs)
// to hide L2 latency. C staged in LDS (stride 116); wave-private copy-out,
// no barriers.
__global__ __launch_bounds__(256)
void mt_both(const float* __restrict__ eatt,   // [NE][100] original order
             const int* __restrict__ eord,     // [NE] CSR pos -> edge id
             const __bf16* __restrict__ Wt,    // [4][128][128]
             __bf16* __restrict__ MT1,         // [NE][112] CSR order
             __bf16* __restrict__ MT2)         // [NE][112] CSR order
{
    __shared__ __align__(16) __bf16 ct[128 * 116];   // 29.7 KB
    const int t = threadIdx.x;
    const int lane = t & 63, w = t >> 6;
    const int l15 = lane & 15, l4 = lane >> 4;
    const size_t row0 = (size_t)blockIdx.x * 128;
    const int half = (row0 >= EHALF) ? 1 : 0;
    const int rbase = w * 32;
    const int wko = l4 * 8;                       // this lane's k-offset in W rows

    const __bf16* Wq0 = Wt + (size_t)half * 16384;
    const __bf16* Wq1 = Wt + (size_t)(2 + half) * 16384;

    // A fragments gathered + converted once (reused for both convs)
    bf16x8 af[2][4];
    {
        const float* ep[2];
        #pragma unroll
        for (int mt = 0; mt < 2; ++mt) {
            size_t row = row0 + rbase + mt * 16 + l15;
            ep[mt] = eatt + (size_t)eord[row] * 100;
        }
        #pragma unroll
        for (int ks = 0; ks < 4; ++ks) {
            const int bk = ks * 32 + wko;
            #pragma unroll
            for (int mt = 0; mt < 2; ++mt) {
                float4 v0 = {0.f, 0.f, 0.f, 0.f}, v1 = {0.f, 0.f, 0.f, 0.f};
                if (bk < 100)     v0 = *(const float4*)(ep[mt] + bk);
                if (bk + 4 < 100) v1 = *(const float4*)(ep[mt] + bk + 4);
                bf16x8 a;
                a[0] = (__bf16)v0.x; a[1] = (__bf16)v0.y;
                a[2] = (__bf16)v0.z; a[3] = (__bf16)v0.w;
                a[4] = (__bf16)v1.x; a[5] = (__bf16)v1.y;
                a[6] = (__bf16)v1.z; a[7] = (__bf16)v1.w;
                af[mt][ks] = a;
            }
        }
    }

    // prime the W pipeline: conv0, nt=0
    bf16x8 wfp[4];
    #pragma unroll
    for (int ks = 0; ks < 4; ++ks)
        wfp[ks] = *(const bf16x8*)(Wq0 + (l15) * 128 + ks * 32 + wko);

    #pragma unroll 1
    for (int conv = 0; conv < 2; ++conv) {
        const __bf16* Wq = conv ? Wq1 : Wq0;
        __bf16* MT = conv ? MT2 : MT1;

        #pragma unroll 1
        for (int nt = 0; nt < 7; ++nt) {
            const int col = nt * 16 + l15;
            bf16x8 wfn[4];
            #pragma unroll
            for (int ks = 0; ks < 4; ++ks) wfn[ks] = wfp[ks];
            // prefetch next fragments (next nt, or next conv's nt=0)
            const __bf16* pf = (nt < 6) ? (Wq + (col + 16) * 128)
                             : (conv == 0 ? (Wq1 + l15 * 128) : nullptr);
            if (pf) {
                #pragma unroll
                for (int ks = 0; ks < 4; ++ks)
                    wfp[ks] = *(const bf16x8*)(pf + ks * 32 + wko);
            }
            f32x4 c4[2] = {};
            #pragma unroll
            for (int ks = 0; ks < 4; ++ks) {
                c4[0] = __builtin_amdgcn_mfma_f32_16x16x32_bf16(
                    af[0][ks], wfn[ks], c4[0], 0, 0, 0);
                c4[1] = __builtin_amdgcn_mfma_f32_16x16x32_bf16(
                    af[1][ks], wfn[ks], c4[1], 0, 0, 0);
            }
            #pragma unroll
            for (int mt = 0; mt < 2; ++mt)
                #pragma unroll
                for (int r = 0; r < 4; ++r)
                    ct[(rbase + mt * 16 + l4 * 4 + r) * 116 + col] =
                        (__bf16)c4[mt][r];
        }

        // wave-private copy-out: rows [rbase,+32) x cols 0..111
        __bf16* gout = MT + (row0 + rbase) * 112;
        #pragma unroll
        for (int k = 0; k < 14; ++k) {
            int i = lane + 64 * k;
            int row = i / 28, ch = i - row * 28;
            *(uint2*)(gout + row * 112 + ch * 4) =
                *(const uint2*)(ct + (rbase + row) * 116 + ch * 4);
        }
    }
}

// ---------------- edge_aggr3: both phases, register accumulation ----------
// MT is CSR-ordered: row index == CSR position (sequential reads). Wave owns
// ONE dst node; lane owns column pair. NT[dst] once per phase; self fused.
template<int ND, int NTS>
__global__ __launch_bounds__(256)
void edge_aggr3(const __bf16* __restrict__ MT,    // [NE][112] CSR order
                const int* __restrict__ srcp,     // [NE] src per CSR position
                const int* __restrict__ off,      // [NN2]
                const __bf16* __restrict__ NT,    // [NN][NTS] bf16
                const float* __restrict__ self,   // [NN][ND] fp32
                float* __restrict__ aggr,         // [NN][112]
                int blkd0, int blks0, int blkd1, int blks1)
{
    const int t = threadIdx.x;
    const int lane = t & 63, wv = t >> 6;
    const int c0 = lane * 2;
    const bool a0 = c0 < ND, a1 = c0 + 1 < ND;
    const int n = blockIdx.x * 4 + wv;     // one node per wave

    float acc0 = 0.f, acc1 = 0.f;

    #pragma unroll
    for (int phase = 0; phase < 2; ++phase) {
        const int blkd = phase ? blkd1 : blkd0;
        const int blks = phase ? blks1 : blks0;
        const int idx = phase * NN + n;
        const int pb = off[idx];
        const int pe = (idx + 1 == NN2) ? NE : off[idx + 1];

        float nd0 = 0.f, nd1 = 0.f;
        if (a0) {
            unsigned nd = *(const unsigned*)(NT + (size_t)n * NTS + blkd + c0);
            nd0 = bf16lo(nd); nd1 = bf16hi(nd);
        }

        for (int p = pb; p < pe; p += GB) {
            int ok[GB], ss[GB];
            #pragma unroll
            for (int i = 0; i < GB; ++i) {
                int pp = p + i;
                ok[i] = pp < pe;
                ss[i] = ok[i] ? srcp[pp] : 0;
            }
            unsigned mtw[GB], nsw[GB];
            #pragma unroll
            for (int i = 0; i < GB; ++i) {
                mtw[i] = 0u; nsw[i] = 0u;
                if (ok[i] && a0) {
                    mtw[i] = *(const unsigned*)(MT + (size_t)(p + i) * 112 + c0);
                    nsw[i] = *(const unsigned*)(NT + (size_t)ss[i] * NTS + blks + c0);
                }
            }
            #pragma unroll
            for (int i = 0; i < GB; ++i) {
                if (!ok[i]) continue;             // wave-uniform
                acc0 += fmaxf(bf16lo(mtw[i]) + nd0 + bf16lo(nsw[i]), 0.f);
                acc1 += fmaxf(bf16hi(mtw[i]) + nd1 + bf16hi(nsw[i]), 0.f);
            }
        }
    }

    if (c0 < 112) {
        const size_t g0 = (size_t)n * 112 + c0;
        aggr[g0]     = a0 ? (acc0 + self[(size_t)n * ND + c0])     : 0.f;
        aggr[g0 + 1] = a1 ? (acc1 + self[(size_t)n * ND + c0 + 1]) : 0.f;
    }
}

// ---- weight assembly: padded concat blocks + transposed mid blocks -------
__global__ void assemble(const float* __restrict__ l1a, const float* __restrict__ l1ab,
                         const float* __restrict__ l1b, const float* __restrict__ l1bb,
                         const float* __restrict__ l2a, const float* __restrict__ l2ab,
                         const float* __restrict__ l2b, const float* __restrict__ l2bb,
                         float* __restrict__ W1, float* __restrict__ b1,
                         float* __restrict__ W2, float* __restrict__ b2,
                         __bf16* __restrict__ Wt)
{
    int i = blockIdx.x * 256 + threadIdx.x;
    if (i < 107 * 432) {
        int k = i / 432, c = i % 432;
        int q = c / 108, cc = c - q * 108;
        float v = 0.f;
        if (cc < 107) {
            if (q == 0)      v = l1a[k * 107 + cc];
            else if (q == 1) v = l1a[(207 + k) * 107 + cc];
            else if (q == 2) v = l1b[k * 107 + cc];
            else             v = l1b[(207 + k) * 107 + cc];
        }
        W1[i] = v;
    }
    if (i < 432) {
        int q = i / 108, cc = i - q * 108;
        b1[i] = (cc < 107) ? (q == 0 ? l1ab[cc] : (q == 3 ? l1bb[cc] : 0.f)) : 0.f;
    }
    if (i < 100 * 416) {
        int k = i / 416, c = i % 416;
        int q = c / 104, cc = c - q * 104;
        float v = 0.f;
        if (cc < 100) {
            if (q == 0)      v = l2a[k * 100 + cc];
            else if (q == 1) v = l2a[(200 + k) * 100 + cc];
            else if (q == 2) v = l2b[k * 100 + cc];
            else             v = l2b[(200 + k) * 100 + cc];
        }
        W2[i] = v;
    }
    if (i < 416) {
        int q = i / 104, cc = i - q * 104;
        b2[i] = (cc < 100) ? (q == 0 ? l2ab[cc] : (q == 3 ? l2bb[cc] : 0.f)) : 0.f;
    }
    if (i < 4 * 128 * 128) {
        int q = i >> 14, col = (i >> 7) & 127, k = i & 127;
        const float* Wm = (q == 0) ? l1a + 107 * 107 :
                          (q == 1) ? l1b + 107 * 107 :
                          (q == 2) ? l2a + 100 * 100 : l2b + 100 * 100;
        int ND = (q < 2) ? 107 : 100;
        float v = (k < 100 && col < ND) ? Wm[k * ND + col] : 0.f;
        Wt[i] = (__bf16)v;
    }
}

// ---- xposeW: transpose all dense-GEMM weights into bf16 [1344][128] ------
__global__ __launch_bounds__(256)
void xposeW(const float* __restrict__ W1, const float* __restrict__ W2,
            const float* __restrict__ m1w1, const float* __restrict__ m1w2,
            const float* __restrict__ m2w1, const float* __restrict__ m2w2,
            __bf16* __restrict__ WT)
{
    int i = blockIdx.x * 256 + threadIdx.x;
    if (i >= 1344 * 128) return;
    int c = i >> 7, k = i & 127;
    const float* src; int lc, cr, K, st;
    if (c < 448)      { src = W1;   lc = c;        cr = 432; K = 107; st = 432; }
    else if (c < 896) { src = W2;   lc = c - 448;  cr = 416; K = 100; st = 416; }
    else if (c < 1024){ src = m1w1; lc = c - 896;  cr = 100; K = 107; st = 100; }
    else if (c < 1152){ src = m1w2; lc = c - 1024; cr = 100; K = 100; st = 100; }
    else if (c < 1216){ src = m2w1; lc = c - 1152; cr = 64;  K = 100; st = 64;  }
    else              { src = m2w2; lc = c - 1216; cr = 100; K = 64;  st = 100; }
    float v = (lc < cr && k < K) ? src[k * st + lc] : 0.f;
    WT[i] = (__bf16)v;
}

extern "C" void kernel_launch(void* const* d_in, const int* in_sizes, int n_in,
                              void* d_out, int out_size, void* d_ws, size_t ws_size,
                              hipStream_t stream)
{
    const float* x    = (const float*)d_in[0];
    const int*   eidx = (const int*)d_in[1];
    const float* eatt = (const float*)d_in[2];
    const float* l1aw = (const float*)d_in[3];
    const float* l1ab = (const float*)d_in[4];
    const float* l1bw = (const float*)d_in[5];
    const float* l1bb = (const float*)d_in[6];
    const float* m1w1 = (const float*)d_in[7];
    const float* m1b1 = (const float*)d_in[8];
    const float* m1w2 = (const float*)d_in[9];
    const float* m1b2 = (const float*)d_in[10];
    const float* l2aw = (const float*)d_in[11];
    const float* l2ab = (const float*)d_in[12];
    const float* l2bw = (const float*)d_in[13];
    const float* l2bb = (const float*)d_in[14];
    const float* m2w1 = (const float*)d_in[15];
    const float* m2b1 = (const float*)d_in[16];
    const float* m2w2 = (const float*)d_in[17];
    const float* m2b2 = (const float*)d_in[18];
    float* out = (float*)d_out;

    // workspace layout (4-byte units), ~450 MB
    float*  ws   = (float*)d_ws;
    __bf16* NTbf = (__bf16*)ws;                         // 50000*432 bf16
    float*  bufA = ws + 10800000;                       // 50000*112 fp32
    float*  bufC = bufA + 5600000;                      // 50000*100 fp32 (h)
    float*  W1   = bufC + 5000000;                      // 46,224
    float*  b1v  = W1 + 46224;                          // 432
    float*  W2   = b1v + 432;                           // 41,600
    float*  b2v  = W2 + 41600;                          // 416
    __bf16* Wt   = (__bf16*)(b2v + 416);                // 4*128*128 bf16
    __bf16* WT   = Wt + 65536;                          // 1344*128 bf16
    int*    off  = (int*)(WT + 172032);                 // 100,000
    int*    cur  = off + NN2;                           // 100,000
    int*    bsum = cur + NN2;                           // 512
    int*    srcp = bsum + 512;                          // 800,000
    int*    eord = srcp + NE;                           // 800,000
    __bf16* MT1  = (__bf16*)(eord + NE);                // NE*112 bf16
    __bf16* MT2  = MT1 + (size_t)NE * 112;              // NE*112 bf16
    float*  bufB = (float*)MT1;                         // t1/t2 alias (MT1 consumed)

    const int* dst = eidx + NE;

    assemble<<<256, 256, 0, stream>>>(l1aw, l1ab, l1bw, l1bb, l2aw, l2ab, l2bw, l2bb,
                                      W1, b1v, W2, b2v, Wt);
    xposeW<<<672, 256, 0, stream>>>(W1, W2, m1w1, m1w2, m2w1, m2w2, WT);

    // ---- CSR build (dst-sorted, per half; emits srcp/eord) ----
    zero_ints<<<(NN2 + 255) / 256, 256, 0, stream>>>(cur, NN2);
    count_edges<<<(NE + 255) / 256, 256, 0, stream>>>(dst, cur);
    scan_blocks<<<(NN2 + 255) / 256, 256, 0, stream>>>(cur, off, bsum, NN2);
    scan_bsum<<<1, 512, 0, stream>>>(bsum, (NN2 + 255) / 256);
    scan_add<<<(NN2 + 255) / 256, 256, 0, stream>>>(off, bsum, cur, NN2);
    scatter_edges<<<(NE + 255) / 256, 256, 0, stream>>>(eidx, cur, srcp, eord);

    // ---- both convs' edge mid-GEMMs (A gathered once, W pipelined) ----
    mt_both<<<6250, 256, 0, stream>>>(eatt, eord, Wt, MT1, MT2);

    const int AG = NN / 4;   // 12500 blocks: 4 waves x 1 node each

    // ---- conv1 ----
    mm_bf16t<107, true><<<dim3(391, 7), 256, 0, stream>>>(x, WT, b1v, NTbf,
                                                          NN, 432, 432, 1, 0);
    edge_aggr3<107, 432><<<AG, 256, 0, stream>>>(MT1, srcp, off, NTbf, x, bufA,
                                                 0, 108, 324, 216);
    mm_bf16t<112, false><<<dim3(391, 2), 256, 0, stream>>>(bufA, WT + 896 * 128,
                                                           m1b1, bufB, NN, 100, 100, 1, 1);
    mm_bf16t<100, false><<<dim3(391, 2), 256, 0, stream>>>(bufB, WT + 1024 * 128,
                                                           m1b2, bufC, NN, 100, 100, 1, 1);

    // ---- conv2 ----  (h in bufC)
    mm_bf16t<100, true><<<dim3(391, 7), 256, 0, stream>>>(bufC, WT + 448 * 128,
                                                          b2v, NTbf, NN, 416, 416, 1, 0);
    edge_aggr3<100, 416><<<AG, 256, 0, stream>>>(MT2, srcp, off, NTbf, bufC, bufA,
                                                 0, 104, 312, 208);
    mm_bf16t<112, false><<<dim3(391, 1), 256, 0, stream>>>(bufA, WT + 1152 * 128,
                                                           m2b1, bufB, NN, 64, 64, 1, 1);
    mm_bf16t<64, false><<<dim3(391, 2), 256, 0, stream>>>(bufB, WT + 1216 * 128,
                                                          m2b2, out, NN, 100, 100, 1, 0);
}